// Round 10
// baseline (187.481 us; speedup 1.0000x reference)
//
#include <hip/hip_runtime.h>
#include <hip/hip_bf16.h>

typedef __attribute__((ext_vector_type(8))) short short8;
typedef __attribute__((ext_vector_type(4))) float f32x4;

#define S_LEN 2048
#define NH 16
#define NKV 8
#define HD 64
#define WIN 512
#define DMODEL 1024
#define LOG2_10000 13.287712379549449f

// async 16B global -> LDS (wave-uniform LDS base + lane*16 semantics)
#define GLOAD16(g, l)                                                        \
    __builtin_amdgcn_global_load_lds(                                        \
        (const __attribute__((address_space(1))) unsigned int*)(g),          \
        (__attribute__((address_space(3))) unsigned int*)(l), 16, 0, 0)

// T1 XCD-aware chunked bijective swizzle (m204; requires nwg % 8 == 0):
// dispatched block `lin` (XCD = lin%8) computes work-tile (lin%8)*(nwg/8)+lin/8
// -> each XCD owns a contiguous chunk of work-tiles, so blocks sharing an
// A-panel / K-V slice land on the same XCD L2.
__device__ __forceinline__ int xcd_swz(int lin, int nwg) {
    return (lin & 7) * (nwg >> 3) + (lin >> 3);
}

// ------- prep: fused X-cast (z=4) + transpose+cast of 4 weights (z=0..3) ----
__global__ void prep_kernel(const float* __restrict__ X,
                            const float* __restrict__ W0,
                            const float* __restrict__ W1,
                            const float* __restrict__ W2,
                            const float* __restrict__ W3,
                            __hip_bfloat16* __restrict__ Xb,
                            __hip_bfloat16* __restrict__ WqkvT,
                            __hip_bfloat16* __restrict__ WoT) {
    if (blockIdx.z == 4) {                         // X cast: fp32 -> bf16
        int tid = (blockIdx.y * 32 + blockIdx.x) * 256 + threadIdx.y * 32 + threadIdx.x;
        const float4* Xi = reinterpret_cast<const float4*>(X);
#pragma unroll
        for (int r = 0; r < 4; ++r) {
            int i = tid + r * (1024 * 256);        // float4 index
            float4 v = Xi[i];
            alignas(8) __hip_bfloat16 h[4];
            h[0] = __float2bfloat16(v.x);
            h[1] = __float2bfloat16(v.y);
            h[2] = __float2bfloat16(v.z);
            h[3] = __float2bfloat16(v.w);
            *reinterpret_cast<ushort4*>(Xb + (size_t)i * 4) =
                *reinterpret_cast<ushort4*>(h);
        }
        return;
    }
    __shared__ float tile[32][33];
    const int K = DMODEL;
    const float* W;
    __hip_bfloat16* WT;
    int N;
    switch (blockIdx.z) {
        case 0: W = W0; WT = WqkvT;                          N = 1024; break;
        case 1: W = W1; WT = WqkvT + (size_t)1024 * K;       N = 512;  break;
        case 2: W = W2; WT = WqkvT + (size_t)1536 * K;       N = 512;  break;
        default: W = W3; WT = WoT;                           N = 1024; break;
    }
    if ((int)blockIdx.x * 32 >= N) return;
    int nx = blockIdx.x * 32 + threadIdx.x;
    int k0 = blockIdx.y * 32;
#pragma unroll
    for (int r = 0; r < 4; ++r) {
        int k = k0 + threadIdx.y + r * 8;
        tile[threadIdx.y + r * 8][threadIdx.x] = W[(size_t)k * N + nx];
    }
    __syncthreads();
#pragma unroll
    for (int r = 0; r < 4; ++r) {
        int nn = blockIdx.x * 32 + threadIdx.y + r * 8;
        int kk = k0 + threadIdx.x;
        WT[(size_t)nn * K + kk] = __float2bfloat16(tile[threadIdx.x][threadIdx.y + r * 8]);
    }
}

// ---------- QKV GEMM: 128x128 tile, 4 waves (2x2 of 64x64), BK=64 ----------
// ROUND 17: 64x64 wave-tile: 16 ds_read vs 32 MFMA per wave-iteration —
// MFMA-dominant. Both-sides XOR involution on the 128 B LDS rows (rule #21).
// Grid 512 = 2 blocks/CU: independent blocks overlap each other's drains.
// ROUND 22: + T1 XCD swizzle (new best 146.07).
__global__ __launch_bounds__(256, 2) void gemm_qkv_kernel(
    const __hip_bfloat16* __restrict__ A,
    const __hip_bfloat16* __restrict__ BT,
    __hip_bfloat16* __restrict__ Qo,
    __hip_bfloat16* __restrict__ Ko,
    __hip_bfloat16* __restrict__ VTo) {
    const int K = DMODEL;
    __shared__ __hip_bfloat16 ldsA[2][128 * 64];   // 32 KB
    __shared__ __hip_bfloat16 ldsB[2][128 * 64];   // 32 KB
    const int tx = threadIdx.x;
    const int wave = tx >> 6;
    const int lane = tx & 63;
    const int l16 = lane & 15;
    const int quad = lane >> 4;
    const int swz = xcd_swz(blockIdx.x + 16 * blockIdx.y, 512);
    const int col0 = (swz & 15) * 128;
    const int row0 = (swz >> 4) * 128;
    const int wrow = (wave >> 1) * 64;
    const int wcol = (wave & 1) * 64;
    const int sw = l16 & 7;                        // reader swizzle key

    f32x4 acc[4][4] = {};

    // staging: row = tx>>3 (0..31), chunk = tx&7, XOR source swizzle
    const int arow = tx >> 3;
    const int cs8 = ((tx & 7) ^ (arow & 7)) * 8;   // swizzled source chunk
    const __hip_bfloat16* gA = A + (size_t)(row0 + arow) * K + cs8;
    const __hip_bfloat16* gB = BT + (size_t)(col0 + arow) * K + cs8;

    auto stage = [&](int k0, int bf) {
        char* lA = (char*)(&ldsA[bf][0]) + tx * 16;
        char* lB = (char*)(&ldsB[bf][0]) + tx * 16;
#pragma unroll
        for (int r = 0; r < 4; ++r) {              // rows r*32 .. r*32+31
            GLOAD16(gA + (size_t)(r * 32) * K + k0, lA + r * 4096);
            GLOAD16(gB + (size_t)(r * 32) * K + k0, lB + r * 4096);
        }
    };

    stage(0, 0);
    int buf = 0;
    for (int k0 = 0; k0 < K; k0 += 64) {
        __syncthreads();                            // drains DMA into [buf]
        if (k0 + 64 < K) stage(k0 + 64, buf ^ 1);   // lands by next barrier
        short8 af[4][2], bf4[4][2];
#pragma unroll
        for (int i = 0; i < 4; ++i) {
            const char* ar = (const char*)(&ldsA[buf][0]) + (wrow + i * 16 + l16) * 128;
            const char* br = (const char*)(&ldsB[buf][0]) + (wcol + i * 16 + l16) * 128;
#pragma unroll
            for (int ks = 0; ks < 2; ++ks) {
                af[i][ks] = *reinterpret_cast<const short8*>(
                    ar + (((ks * 4 + quad) ^ sw) << 4));
                bf4[i][ks] = *reinterpret_cast<const short8*>(
                    br + (((ks * 4 + quad) ^ sw) << 4));
            }
        }
#pragma unroll
        for (int ks = 0; ks < 2; ++ks)
#pragma unroll
            for (int mi = 0; mi < 4; ++mi)
#pragma unroll
                for (int ni = 0; ni < 4; ++ni)
                    acc[mi][ni] = __builtin_amdgcn_mfma_f32_16x16x32_bf16(
                        af[mi][ks], bf4[ni][ks], acc[mi][ni], 0, 0, 0);
        buf ^= 1;
    }

    const int rbase = row0 + wrow;
    const int cbaseg = col0 + wcol;                 // 64-aligned global col
    const bool isQ = (cbaseg < DMODEL);
    const bool isK = (cbaseg >= DMODEL) && (cbaseg < DMODEL + 512);
    if (isQ || isK) {
        float invf[2];
        invf[0] = exp2f(-(float)(l16)      * (LOG2_10000 / 32.0f));
        invf[1] = exp2f(-(float)(16 + l16) * (LOG2_10000 / 32.0f));
#pragma unroll
        for (int mi = 0; mi < 4; ++mi)
#pragma unroll
            for (int r = 0; r < 4; ++r) {
                int srow = (rbase + mi * 16 + quad * 4 + r) & (S_LEN - 1);
#pragma unroll
                for (int ni = 0; ni < 2; ++ni) {
                    float ang = (float)srow * invf[ni];
                    float c = __cosf(ang), s = __sinf(ang);
                    float x1 = acc[mi][ni][r], x2 = acc[mi][ni + 2][r];
                    acc[mi][ni][r]     = x1 * c - x2 * s;
                    acc[mi][ni + 2][r] = x2 * c + x1 * s;
                }
            }
        __hip_bfloat16* Co = isQ ? Qo : Ko;
        int cbase = isQ ? cbaseg : cbaseg - DMODEL;
        int rowstride = isQ ? (NH * HD) : (NKV * HD);
#pragma unroll
        for (int mi = 0; mi < 4; ++mi)
#pragma unroll
            for (int ni = 0; ni < 4; ++ni) {
                size_t col = cbase + ni * 16 + l16;
#pragma unroll
                for (int r = 0; r < 4; ++r)
                    Co[(size_t)(rbase + mi * 16 + quad * 4 + r) * rowstride + col] =
                        __float2bfloat16(acc[mi][ni][r]);
            }
    } else {                                       // V region -> transposed VT
        int bb = row0 >> 11;
#pragma unroll
        for (int mi = 0; mi < 4; ++mi) {
            int s = ((rbase + mi * 16 + quad * 4) & (S_LEN - 1));
#pragma unroll
            for (int ni = 0; ni < 4; ++ni) {
                int colv = cbaseg - 1536 + ni * 16 + l16;   // 0..511
                int vh = colv >> 6, d = colv & 63;
                alignas(8) __hip_bfloat16 hv[4];
#pragma unroll
                for (int r = 0; r < 4; ++r) hv[r] = __float2bfloat16(acc[mi][ni][r]);
                *reinterpret_cast<ushort4*>(
                    VTo + ((size_t)(bb * NKV + vh) * HD + d) * S_LEN + s) =
                    *reinterpret_cast<ushort4*>(hv);
            }
        }
    }
}

// ------- out-proj GEMM: 128(M)x64(N) tile, 4 waves of 32x64, BK=64 -------
// r16 measured-best config. Five variants tried (r18 128x128, r19 2-wave,
// r21 split-K atomics) all regressed — FROZEN structurally. + T1 swizzle.
__global__ __launch_bounds__(256, 4) void gemm_op_kernel(
    const __hip_bfloat16* __restrict__ A,
    const __hip_bfloat16* __restrict__ BT,
    float* __restrict__ Co, int N, int K) {
    __shared__ __hip_bfloat16 ldsA[2][128 * 64];   // 32 KB
    __shared__ __hip_bfloat16 ldsB[2][64 * 64];    // 16 KB
    const int tx = threadIdx.x;
    const int wave = tx >> 6;
    const int lane = tx & 63;
    const int l16 = lane & 15;
    const int quad = lane >> 4;
    const int swz = xcd_swz(blockIdx.x + 16 * blockIdx.y, 512);
    const int col0 = (swz & 15) * 64;
    const int row0 = (swz >> 4) * 128;
    const int wrow = wave * 32;
    const int sw = l16 & 7;                        // reader swizzle key

    f32x4 acc[2][4] = {};

    // staging: row = tx>>3 (0..31), chunk = tx&7, XOR source swizzle
    const int arow = tx >> 3;
    const int cs8 = ((tx & 7) ^ (arow & 7)) * 8;   // swizzled source chunk
    const __hip_bfloat16* gA = A + (size_t)(row0 + arow) * K + cs8;
    const __hip_bfloat16* gB = BT + (size_t)(col0 + arow) * K + cs8;

    auto stage = [&](int k0, int bf) {
        char* lA = (char*)(&ldsA[bf][0]) + tx * 16;
        char* lB = (char*)(&ldsB[bf][0]) + tx * 16;
#pragma unroll
        for (int r = 0; r < 4; ++r)                // A rows r*32 .. r*32+31
            GLOAD16(gA + (size_t)(r * 32) * K + k0, lA + r * 4096);
#pragma unroll
        for (int r = 0; r < 2; ++r)                // B rows r*32 .. r*32+31
            GLOAD16(gB + (size_t)(r * 32) * K + k0, lB + r * 4096);
    };

    stage(0, 0);
    int buf = 0;
    for (int k0 = 0; k0 < K; k0 += 64) {
        __syncthreads();                            // drains DMA into [buf]
        if (k0 + 64 < K) stage(k0 + 64, buf ^ 1);   // lands by next barrier
        short8 af[2][2], bf4[4][2];
#pragma unroll
        for (int i = 0; i < 2; ++i) {
            const char* ar = (const char*)(&ldsA[buf][0]) + (wrow + i * 16 + l16) * 128;
#pragma unroll
            for (int ks = 0; ks < 2; ++ks)
                af[i][ks] = *reinterpret_cast<const short8*>(
                    ar + (((ks * 4 + quad) ^ sw) << 4));
        }
#pragma unroll
        for (int i = 0; i < 4; ++i) {
            const char* br = (const char*)(&ldsB[buf][0]) + (i * 16 + l16) * 128;
#pragma unroll
            for (int ks = 0; ks < 2; ++ks)
                bf4[i][ks] = *reinterpret_cast<const short8*>(
                    br + (((ks * 4 + quad) ^ sw) << 4));
        }
#pragma unroll
        for (int ks = 0; ks < 2; ++ks)
#pragma unroll
            for (int mi = 0; mi < 2; ++mi)
#pragma unroll
                for (int ni = 0; ni < 4; ++ni)
                    acc[mi][ni] = __builtin_amdgcn_mfma_f32_16x16x32_bf16(
                        af[mi][ks], bf4[ni][ks], acc[mi][ni], 0, 0, 0);
        buf ^= 1;
    }

    const int rbase = row0 + wrow;
#pragma unroll
    for (int mi = 0; mi < 2; ++mi)
#pragma unroll
        for (int ni = 0; ni < 4; ++ni) {
            size_t col = col0 + ni * 16 + l16;
#pragma unroll
            for (int r = 0; r < 4; ++r)
                Co[(size_t)(rbase + mi * 16 + quad * 4 + r) * N + col] = acc[mi][ni][r];
        }
}

// ------- MFMA flash attention: direct-L2 K/V reads, barrier-free -------
// ROUND 23: with T1 each XCD's 128 work-tiles share 4 (h,b) K+VT slices =
// 2 MB — L2-resident. Per Common-mistake #7 / m169, LDS-staging L2-fitting
// data is pure overhead: K/V fragments are now read DIRECTLY from global
// (the LDS source/reader swizzles cancel: bk0 at d=quad*8, bk1 at 32+quad*8
// — same layout as the Q fragments; vf at j=(ks*4+quad)*8). This removes
// ldsK/ldsVT, the DMA double-buffer, and EVERY __syncthreads (ldsP is
// wave-private; same-wave LDS RAW is ordered by compiler lgkmcnt). Each
// fragment load covers 16 rows x 64 B = 16 full cache lines; 16 waves/CU
// of barrier-free TLP hide the ~200 cyc L2 latency (m114).
// T13 defer-max retained. QBLK=64, grid 1024, LDS 8 KB.
__global__ __launch_bounds__(256, 4) void attn_mfma_kernel(
    const __hip_bfloat16* __restrict__ Q,
    const __hip_bfloat16* __restrict__ K,
    const __hip_bfloat16* __restrict__ VT,
    __hip_bfloat16* __restrict__ O) {
    __shared__ __hip_bfloat16 ldsP[4][16][64];       // 8 KB, XOR unit swizzle
    const int tx = threadIdx.x;
    const int wave = tx >> 6;
    const int lane = tx & 63;
    const int l16 = lane & 15;
    const int quad = lane >> 4;
    const int swz = xcd_swz(blockIdx.x + 32 * (blockIdx.y + 16 * blockIdx.z), 1024);
    const int q0 = (swz & 31) * 64;
    const int h = (swz >> 5) & 15;
    const int b = swz >> 9;
    const int kvh = h >> 1;
    const int qi = q0 + wave * 16 + l16;

    short8 aq[2];
    {
        const __hip_bfloat16* qp =
            Q + (size_t)(b * S_LEN + qi) * (NH * HD) + h * HD + quad * 8;
        aq[0] = *reinterpret_cast<const short8*>(qp);
        aq[1] = *reinterpret_cast<const short8*>(qp + 32);
    }
    f32x4 acc_o[4] = {};
    float m = -1e30f, l = 0.f;
    const float SL2 = 0.125f * 1.4426950408889634f;   // scale * log2(e)

    const __hip_bfloat16* Kbase =
        K + (size_t)b * S_LEN * (NKV * HD) + kvh * HD + quad * 8;
    const __hip_bfloat16* Vbase =
        VT + ((size_t)(b * NKV + kvh) * HD + l16) * S_LEN;

    const int kstart = (q0 >= WIN) ? (q0 - WIN) : 0;
    char* prow = (char*)(&ldsP[wave][l16][0]);

    for (int j0 = kstart; j0 <= q0; j0 += 64) {
        // S^T = K @ Q^T — K fragments direct from global (L2-hot)
        f32x4 sacc[4] = {};
#pragma unroll
        for (int t = 0; t < 4; ++t) {
            const __hip_bfloat16* krow =
                Kbase + (size_t)(j0 + t * 16 + l16) * (NKV * HD);
            short8 bk0 = *reinterpret_cast<const short8*>(krow);
            short8 bk1 = *reinterpret_cast<const short8*>(krow + 32);
            sacc[t] = __builtin_amdgcn_mfma_f32_16x16x32_bf16(bk0, aq[0], sacc[t], 0, 0, 0);
            sacc[t] = __builtin_amdgcn_mfma_f32_16x16x32_bf16(bk1, aq[1], sacc[t], 0, 0, 0);
        }

        const bool need_mask = (j0 == q0) || (q0 >= WIN && j0 == kstart);
        float sv[4][4];
        if (need_mask) {
#pragma unroll
            for (int t = 0; t < 4; ++t)
#pragma unroll
                for (int r = 0; r < 4; ++r) {
                    int j = j0 + t * 16 + quad * 4 + r;
                    bool ok = (j <= qi) && (j + WIN >= qi);
                    sv[t][r] = ok ? sacc[t][r] * SL2 : -1e30f;
                }
        } else {
#pragma unroll
            for (int t = 0; t < 4; ++t)
#pragma unroll
                for (int r = 0; r < 4; ++r) sv[t][r] = sacc[t][r] * SL2;
        }
        // online softmax (exp2 domain): in-lane reduce + 2 shuffles
        float cm = -1e30f;
#pragma unroll
        for (int t = 0; t < 4; ++t)
#pragma unroll
            for (int r = 0; r < 4; ++r) cm = fmaxf(cm, sv[t][r]);
        cm = fmaxf(cm, __shfl_xor(cm, 16));
        cm = fmaxf(cm, __shfl_xor(cm, 32));
        // T13 defer-max: skip rescale while the tile max stays within 8
        // (exp2 domain) of the running max; P then bounded by 2^8 = 256.
        if (!__all(cm - m <= 8.0f)) {
            float mn = fmaxf(m, cm);
            float alpha = exp2f(m - mn);
            m = mn;
            l *= alpha;
#pragma unroll
            for (int t = 0; t < 4; ++t)
#pragma unroll
                for (int r = 0; r < 4; ++r) acc_o[t][r] *= alpha;
        }
        float sp = 0.f;
#pragma unroll
        for (int t = 0; t < 4; ++t)
#pragma unroll
            for (int r = 0; r < 4; ++r) { sv[t][r] = exp2f(sv[t][r] - m); sp += sv[t][r]; }
        sp += __shfl_xor(sp, 16);
        sp += __shfl_xor(sp, 32);
        l += sp;
        // P^T -> LDS (XOR unit swizzle; wave-private, in-order)
#pragma unroll
        for (int t = 0; t < 4; ++t) {
            alignas(8) __hip_bfloat16 hp[4];
#pragma unroll
            for (int r = 0; r < 4; ++r) hp[r] = __float2bfloat16(sv[t][r]);
            int swb = ((((2 * t + (quad >> 1)) ^ (l16 & 7)) << 4) | ((quad & 1) << 3));
            *reinterpret_cast<ushort4*>(prow + swb) = *reinterpret_cast<ushort4*>(hp);
        }

        // O^T += VT @ P^T — VT fragments direct from global (L2-hot)
#pragma unroll
        for (int ks = 0; ks < 2; ++ks) {
            short8 pf = *reinterpret_cast<const short8*>(
                prow + (((4 * ks + quad) ^ (l16 & 7)) << 4));
#pragma unroll
            for (int t = 0; t < 4; ++t) {
                const __hip_bfloat16* vrow =
                    Vbase + (size_t)(t * 16) * S_LEN + j0 + (ks * 4 + quad) * 8;
                short8 vf = *reinterpret_cast<const short8*>(vrow);
                acc_o[t] = __builtin_amdgcn_mfma_f32_16x16x32_bf16(vf, pf, acc_o[t], 0, 0, 0);
            }
        }
    }

    {
        float inv = 1.f / l;
        __hip_bfloat16* op =
            O + (size_t)(b * S_LEN + qi) * (NH * HD) + h * HD;
#pragma unroll
        for (int t = 0; t < 4; ++t) {
            alignas(8) __hip_bfloat16 ho[4];
#pragma unroll
            for (int r = 0; r < 4; ++r) ho[r] = __float2bfloat16(acc_o[t][r] * inv);
            *reinterpret_cast<ushort4*>(op + t * 16 + quad * 4) =
                *reinterpret_cast<ushort4*>(ho);
        }
    }
}

// ---------------- launch ----------------
extern "C" void kernel_launch(void* const* d_in, const int* in_sizes, int n_in,
                              void* d_out, int out_size, void* d_ws, size_t ws_size,
                              hipStream_t stream) {
    const float* X  = (const float*)d_in[0];
    const float* Wq = (const float*)d_in[1];
    const float* Wk = (const float*)d_in[2];
    const float* Wv = (const float*)d_in[3];
    const float* Wo = (const float*)d_in[4];
    float* out = (float*)d_out;

    const int ROWS = 2 * S_LEN;               // 4096
    char* ws = (char*)d_ws;
    size_t off = 0;
    __hip_bfloat16* Xb     = (__hip_bfloat16*)(ws + off); off += (size_t)ROWS * DMODEL * 2;
    __hip_bfloat16* WqkvT  = (__hip_bfloat16*)(ws + off); off += (size_t)2048 * DMODEL * 2;
    __hip_bfloat16* WoT    = (__hip_bfloat16*)(ws + off); off += (size_t)DMODEL * DMODEL * 2;
    __hip_bfloat16* Qb     = (__hip_bfloat16*)(ws + off); off += (size_t)ROWS * (NH * HD) * 2;
    __hip_bfloat16* Kb     = (__hip_bfloat16*)(ws + off); off += (size_t)ROWS * (NKV * HD) * 2;
    __hip_bfloat16* VTg    = (__hip_bfloat16*)(ws + off); off += (size_t)ROWS * (NKV * HD) * 2;
    __hip_bfloat16* Ob     = (__hip_bfloat16*)(ws + off); off += (size_t)ROWS * (NH * HD) * 2;

    // 1. fused prep: X cast (z=4) + all weight transposes (z=0..3)
    prep_kernel<<<dim3(32, 32, 5), dim3(32, 8), 0, stream>>>(
        X, Wq, Wk, Wv, Wo, Xb, WqkvT, WoT);

    // 2. fused QKV projection + RoPE + V transpose (128x128 tile, 512 blocks)
    gemm_qkv_kernel<<<dim3(2048 / 128, ROWS / 128), 256, 0, stream>>>(
        Xb, WqkvT, Qb, Kb, VTg);

    // 3. MFMA flash attention (direct-L2 K/V, barrier-free)
    attn_mfma_kernel<<<dim3(S_LEN / 64, NH, 2), 256, 0, stream>>>(Qb, Kb, VTg, Ob);

    // 4. output projection -> fp32 (r16 measured-best config)
    gemm_op_kernel<<<dim3(DMODEL / 64, ROWS / 128), 256, 0, stream>>>(
        Ob, WoT, out, DMODEL, DMODEL);
}

// Round 11
// 146.564 us; speedup vs baseline: 1.2792x; 1.2792x over previous
//
#include <hip/hip_runtime.h>
#include <hip/hip_bf16.h>

typedef __attribute__((ext_vector_type(8))) short short8;
typedef __attribute__((ext_vector_type(4))) float f32x4;

#define S_LEN 2048
#define NH 16
#define NKV 8
#define HD 64
#define WIN 512
#define DMODEL 1024
#define LOG2_10000 13.287712379549449f

// async 16B global -> LDS (wave-uniform LDS base + lane*16 semantics)
#define GLOAD16(g, l)                                                        \
    __builtin_amdgcn_global_load_lds(                                        \
        (const __attribute__((address_space(1))) unsigned int*)(g),          \
        (__attribute__((address_space(3))) unsigned int*)(l), 16, 0, 0)

// T1 XCD-aware chunked bijective swizzle (m204; requires nwg % 8 == 0):
// dispatched block `lin` (XCD = lin%8) computes work-tile (lin%8)*(nwg/8)+lin/8
// -> each XCD owns a contiguous chunk of work-tiles, so blocks sharing an
// A-panel / K-V slice land on the same XCD L2.
__device__ __forceinline__ int xcd_swz(int lin, int nwg) {
    return (lin & 7) * (nwg >> 3) + (lin >> 3);
}

// ------- prep: fused X-cast (z=4) + transpose+cast of 4 weights (z=0..3) ----
__global__ void prep_kernel(const float* __restrict__ X,
                            const float* __restrict__ W0,
                            const float* __restrict__ W1,
                            const float* __restrict__ W2,
                            const float* __restrict__ W3,
                            __hip_bfloat16* __restrict__ Xb,
                            __hip_bfloat16* __restrict__ WqkvT,
                            __hip_bfloat16* __restrict__ WoT) {
    if (blockIdx.z == 4) {                         // X cast: fp32 -> bf16
        int tid = (blockIdx.y * 32 + blockIdx.x) * 256 + threadIdx.y * 32 + threadIdx.x;
        const float4* Xi = reinterpret_cast<const float4*>(X);
#pragma unroll
        for (int r = 0; r < 4; ++r) {
            int i = tid + r * (1024 * 256);        // float4 index
            float4 v = Xi[i];
            alignas(8) __hip_bfloat16 h[4];
            h[0] = __float2bfloat16(v.x);
            h[1] = __float2bfloat16(v.y);
            h[2] = __float2bfloat16(v.z);
            h[3] = __float2bfloat16(v.w);
            *reinterpret_cast<ushort4*>(Xb + (size_t)i * 4) =
                *reinterpret_cast<ushort4*>(h);
        }
        return;
    }
    __shared__ float tile[32][33];
    const int K = DMODEL;
    const float* W;
    __hip_bfloat16* WT;
    int N;
    switch (blockIdx.z) {
        case 0: W = W0; WT = WqkvT;                          N = 1024; break;
        case 1: W = W1; WT = WqkvT + (size_t)1024 * K;       N = 512;  break;
        case 2: W = W2; WT = WqkvT + (size_t)1536 * K;       N = 512;  break;
        default: W = W3; WT = WoT;                           N = 1024; break;
    }
    if ((int)blockIdx.x * 32 >= N) return;
    int nx = blockIdx.x * 32 + threadIdx.x;
    int k0 = blockIdx.y * 32;
#pragma unroll
    for (int r = 0; r < 4; ++r) {
        int k = k0 + threadIdx.y + r * 8;
        tile[threadIdx.y + r * 8][threadIdx.x] = W[(size_t)k * N + nx];
    }
    __syncthreads();
#pragma unroll
    for (int r = 0; r < 4; ++r) {
        int nn = blockIdx.x * 32 + threadIdx.y + r * 8;
        int kk = k0 + threadIdx.x;
        WT[(size_t)nn * K + kk] = __float2bfloat16(tile[threadIdx.x][threadIdx.y + r * 8]);
    }
}

// ---------- QKV GEMM: 128x128 tile, 4 waves (2x2 of 64x64), BK=64 ----------
// ROUND 17: 64x64 wave-tile: 16 ds_read vs 32 MFMA per wave-iteration —
// MFMA-dominant. Both-sides XOR involution on the 128 B LDS rows (rule #21).
// Grid 512 = 2 blocks/CU: independent blocks overlap each other's drains.
// ROUND 22: + T1 XCD swizzle (measured best 146.07).
__global__ __launch_bounds__(256, 2) void gemm_qkv_kernel(
    const __hip_bfloat16* __restrict__ A,
    const __hip_bfloat16* __restrict__ BT,
    __hip_bfloat16* __restrict__ Qo,
    __hip_bfloat16* __restrict__ Ko,
    __hip_bfloat16* __restrict__ VTo) {
    const int K = DMODEL;
    __shared__ __hip_bfloat16 ldsA[2][128 * 64];   // 32 KB
    __shared__ __hip_bfloat16 ldsB[2][128 * 64];   // 32 KB
    const int tx = threadIdx.x;
    const int wave = tx >> 6;
    const int lane = tx & 63;
    const int l16 = lane & 15;
    const int quad = lane >> 4;
    const int swz = xcd_swz(blockIdx.x + 16 * blockIdx.y, 512);
    const int col0 = (swz & 15) * 128;
    const int row0 = (swz >> 4) * 128;
    const int wrow = (wave >> 1) * 64;
    const int wcol = (wave & 1) * 64;
    const int sw = l16 & 7;                        // reader swizzle key

    f32x4 acc[4][4] = {};

    // staging: row = tx>>3 (0..31), chunk = tx&7, XOR source swizzle
    const int arow = tx >> 3;
    const int cs8 = ((tx & 7) ^ (arow & 7)) * 8;   // swizzled source chunk
    const __hip_bfloat16* gA = A + (size_t)(row0 + arow) * K + cs8;
    const __hip_bfloat16* gB = BT + (size_t)(col0 + arow) * K + cs8;

    auto stage = [&](int k0, int bf) {
        char* lA = (char*)(&ldsA[bf][0]) + tx * 16;
        char* lB = (char*)(&ldsB[bf][0]) + tx * 16;
#pragma unroll
        for (int r = 0; r < 4; ++r) {              // rows r*32 .. r*32+31
            GLOAD16(gA + (size_t)(r * 32) * K + k0, lA + r * 4096);
            GLOAD16(gB + (size_t)(r * 32) * K + k0, lB + r * 4096);
        }
    };

    stage(0, 0);
    int buf = 0;
    for (int k0 = 0; k0 < K; k0 += 64) {
        __syncthreads();                            // drains DMA into [buf]
        if (k0 + 64 < K) stage(k0 + 64, buf ^ 1);   // lands by next barrier
        short8 af[4][2], bf4[4][2];
#pragma unroll
        for (int i = 0; i < 4; ++i) {
            const char* ar = (const char*)(&ldsA[buf][0]) + (wrow + i * 16 + l16) * 128;
            const char* br = (const char*)(&ldsB[buf][0]) + (wcol + i * 16 + l16) * 128;
#pragma unroll
            for (int ks = 0; ks < 2; ++ks) {
                af[i][ks] = *reinterpret_cast<const short8*>(
                    ar + (((ks * 4 + quad) ^ sw) << 4));
                bf4[i][ks] = *reinterpret_cast<const short8*>(
                    br + (((ks * 4 + quad) ^ sw) << 4));
            }
        }
#pragma unroll
        for (int ks = 0; ks < 2; ++ks)
#pragma unroll
            for (int mi = 0; mi < 4; ++mi)
#pragma unroll
                for (int ni = 0; ni < 4; ++ni)
                    acc[mi][ni] = __builtin_amdgcn_mfma_f32_16x16x32_bf16(
                        af[mi][ks], bf4[ni][ks], acc[mi][ni], 0, 0, 0);
        buf ^= 1;
    }

    const int rbase = row0 + wrow;
    const int cbaseg = col0 + wcol;                 // 64-aligned global col
    const bool isQ = (cbaseg < DMODEL);
    const bool isK = (cbaseg >= DMODEL) && (cbaseg < DMODEL + 512);
    if (isQ || isK) {
        float invf[2];
        invf[0] = exp2f(-(float)(l16)      * (LOG2_10000 / 32.0f));
        invf[1] = exp2f(-(float)(16 + l16) * (LOG2_10000 / 32.0f));
#pragma unroll
        for (int mi = 0; mi < 4; ++mi)
#pragma unroll
            for (int r = 0; r < 4; ++r) {
                int srow = (rbase + mi * 16 + quad * 4 + r) & (S_LEN - 1);
#pragma unroll
                for (int ni = 0; ni < 2; ++ni) {
                    float ang = (float)srow * invf[ni];
                    float c = __cosf(ang), s = __sinf(ang);
                    float x1 = acc[mi][ni][r], x2 = acc[mi][ni + 2][r];
                    acc[mi][ni][r]     = x1 * c - x2 * s;
                    acc[mi][ni + 2][r] = x2 * c + x1 * s;
                }
            }
        __hip_bfloat16* Co = isQ ? Qo : Ko;
        int cbase = isQ ? cbaseg : cbaseg - DMODEL;
        int rowstride = isQ ? (NH * HD) : (NKV * HD);
#pragma unroll
        for (int mi = 0; mi < 4; ++mi)
#pragma unroll
            for (int ni = 0; ni < 4; ++ni) {
                size_t col = cbase + ni * 16 + l16;
#pragma unroll
                for (int r = 0; r < 4; ++r)
                    Co[(size_t)(rbase + mi * 16 + quad * 4 + r) * rowstride + col] =
                        __float2bfloat16(acc[mi][ni][r]);
            }
    } else {                                       // V region -> transposed VT
        int bb = row0 >> 11;
#pragma unroll
        for (int mi = 0; mi < 4; ++mi) {
            int s = ((rbase + mi * 16 + quad * 4) & (S_LEN - 1));
#pragma unroll
            for (int ni = 0; ni < 4; ++ni) {
                int colv = cbaseg - 1536 + ni * 16 + l16;   // 0..511
                int vh = colv >> 6, d = colv & 63;
                alignas(8) __hip_bfloat16 hv[4];
#pragma unroll
                for (int r = 0; r < 4; ++r) hv[r] = __float2bfloat16(acc[mi][ni][r]);
                *reinterpret_cast<ushort4*>(
                    VTo + ((size_t)(bb * NKV + vh) * HD + d) * S_LEN + s) =
                    *reinterpret_cast<ushort4*>(hv);
            }
        }
    }
}

// ------- out-proj GEMM: 128(M)x64(N) tile, 4 waves of 32x64, BK=64 -------
// r16 measured-best config. Five variants tried (r18 128x128, r19 2-wave,
// r21 split-K atomics) all regressed — FROZEN structurally. + T1 swizzle.
__global__ __launch_bounds__(256, 4) void gemm_op_kernel(
    const __hip_bfloat16* __restrict__ A,
    const __hip_bfloat16* __restrict__ BT,
    float* __restrict__ Co, int N, int K) {
    __shared__ __hip_bfloat16 ldsA[2][128 * 64];   // 32 KB
    __shared__ __hip_bfloat16 ldsB[2][64 * 64];    // 16 KB
    const int tx = threadIdx.x;
    const int wave = tx >> 6;
    const int lane = tx & 63;
    const int l16 = lane & 15;
    const int quad = lane >> 4;
    const int swz = xcd_swz(blockIdx.x + 16 * blockIdx.y, 512);
    const int col0 = (swz & 15) * 64;
    const int row0 = (swz >> 4) * 128;
    const int wrow = wave * 32;
    const int sw = l16 & 7;                        // reader swizzle key

    f32x4 acc[2][4] = {};

    // staging: row = tx>>3 (0..31), chunk = tx&7, XOR source swizzle
    const int arow = tx >> 3;
    const int cs8 = ((tx & 7) ^ (arow & 7)) * 8;   // swizzled source chunk
    const __hip_bfloat16* gA = A + (size_t)(row0 + arow) * K + cs8;
    const __hip_bfloat16* gB = BT + (size_t)(col0 + arow) * K + cs8;

    auto stage = [&](int k0, int bf) {
        char* lA = (char*)(&ldsA[bf][0]) + tx * 16;
        char* lB = (char*)(&ldsB[bf][0]) + tx * 16;
#pragma unroll
        for (int r = 0; r < 4; ++r)                // A rows r*32 .. r*32+31
            GLOAD16(gA + (size_t)(r * 32) * K + k0, lA + r * 4096);
#pragma unroll
        for (int r = 0; r < 2; ++r)                // B rows r*32 .. r*32+31
            GLOAD16(gB + (size_t)(r * 32) * K + k0, lB + r * 4096);
    };

    stage(0, 0);
    int buf = 0;
    for (int k0 = 0; k0 < K; k0 += 64) {
        __syncthreads();                            // drains DMA into [buf]
        if (k0 + 64 < K) stage(k0 + 64, buf ^ 1);   // lands by next barrier
        short8 af[2][2], bf4[4][2];
#pragma unroll
        for (int i = 0; i < 2; ++i) {
            const char* ar = (const char*)(&ldsA[buf][0]) + (wrow + i * 16 + l16) * 128;
#pragma unroll
            for (int ks = 0; ks < 2; ++ks)
                af[i][ks] = *reinterpret_cast<const short8*>(
                    ar + (((ks * 4 + quad) ^ sw) << 4));
        }
#pragma unroll
        for (int i = 0; i < 4; ++i) {
            const char* br = (const char*)(&ldsB[buf][0]) + (i * 16 + l16) * 128;
#pragma unroll
            for (int ks = 0; ks < 2; ++ks)
                bf4[i][ks] = *reinterpret_cast<const short8*>(
                    br + (((ks * 4 + quad) ^ sw) << 4));
        }
#pragma unroll
        for (int ks = 0; ks < 2; ++ks)
#pragma unroll
            for (int mi = 0; mi < 2; ++mi)
#pragma unroll
                for (int ni = 0; ni < 4; ++ni)
                    acc[mi][ni] = __builtin_amdgcn_mfma_f32_16x16x32_bf16(
                        af[mi][ks], bf4[ni][ks], acc[mi][ni], 0, 0, 0);
        buf ^= 1;
    }

    const int rbase = row0 + wrow;
#pragma unroll
    for (int mi = 0; mi < 2; ++mi)
#pragma unroll
        for (int ni = 0; ni < 4; ++ni) {
            size_t col = col0 + ni * 16 + l16;
#pragma unroll
            for (int r = 0; r < 4; ++r)
                Co[(size_t)(rbase + mi * 16 + quad * 4 + r) * N + col] = acc[mi][ni][r];
        }
}

// ---------------- MFMA flash attention: head-split, DMA dbuf, swizzled ----
// QBLK=64 measured-best config (r17) + T1 XCD swizzle (r22, 146.07 best).
// r23's direct-L2 variant regressed 4.8x (MfmaUtil 4.4%, FETCH 8.2MB):
// LDS staging is what shares each K/V tile across the block's 4 waves and
// keeps dependent-load latency off the MFMA critical path. FROZEN.
// T13 defer-max retained.
__global__ __launch_bounds__(256, 4) void attn_mfma_kernel(
    const __hip_bfloat16* __restrict__ Q,
    const __hip_bfloat16* __restrict__ K,
    const __hip_bfloat16* __restrict__ VT,
    __hip_bfloat16* __restrict__ O) {
    __shared__ __hip_bfloat16 ldsK[2][64][64];       // 16 KB
    __shared__ __hip_bfloat16 ldsVT[2][64][64];      // 16 KB
    __shared__ __hip_bfloat16 ldsP[4][16][64];       // 8 KB, XOR unit swizzle
    const int tx = threadIdx.x;
    const int wave = tx >> 6;
    const int lane = tx & 63;
    const int l16 = lane & 15;
    const int quad = lane >> 4;
    const int swz = xcd_swz(blockIdx.x + 32 * (blockIdx.y + 16 * blockIdx.z), 1024);
    const int q0 = (swz & 31) * 64;
    const int h = (swz >> 5) & 15;
    const int b = swz >> 9;
    const int kvh = h >> 1;
    const int qi = q0 + wave * 16 + l16;

    short8 aq[2];
    {
        const __hip_bfloat16* qp =
            Q + (size_t)(b * S_LEN + qi) * (NH * HD) + h * HD + quad * 8;
        aq[0] = *reinterpret_cast<const short8*>(qp);
        aq[1] = *reinterpret_cast<const short8*>(qp + 32);
    }
    f32x4 acc_o[4] = {};
    float m = -1e30f, l = 0.f;
    const float SL2 = 0.125f * 1.4426950408889634f;   // scale * log2(e)

    // staging: row = tx>>3 (+32), chunk-in-row = tx&7, XOR source swizzle
    const int s_row = tx >> 3;
    const int s_c8 = (((tx & 7) ^ (s_row & 7))) * 8;
    const int sw = (l16 & 7);                          // reader swizzle key
    auto stage = [&](int j0, int bf) {
        char* lk = (char*)(&ldsK[bf][0][0]) + tx * 16;
        char* lv = (char*)(&ldsVT[bf][0][0]) + tx * 16;
#pragma unroll
        for (int r = 0; r < 2; ++r) {
            int row = s_row + r * 32;
            GLOAD16(K + (size_t)(b * S_LEN + j0 + row) * (NKV * HD) + kvh * HD + s_c8,
                    lk + r * 4096);
            GLOAD16(VT + ((size_t)(b * NKV + kvh) * HD + row) * S_LEN + j0 + s_c8,
                    lv + r * 4096);
        }
    };

    const int kstart = (q0 >= WIN) ? (q0 - WIN) : 0;
    stage(kstart, 0);
    int buf = 0;

    char* prow = (char*)(&ldsP[wave][l16][0]);

    for (int j0 = kstart; j0 <= q0; j0 += 64) {
        __syncthreads();                              // drains DMA into [buf]
        if (j0 + 64 <= q0) stage(j0 + 64, buf ^ 1);   // async, lands by next barrier

        // S^T = K @ Q^T
        f32x4 sacc[4] = {};
#pragma unroll
        for (int t = 0; t < 4; ++t) {
            const __hip_bfloat16* krow = &ldsK[buf][t * 16 + l16][0];
            short8 bk0 = *reinterpret_cast<const short8*>(krow + ((quad ^ sw) * 8));
            short8 bk1 = *reinterpret_cast<const short8*>(krow + (((4 + quad) ^ sw) * 8));
            sacc[t] = __builtin_amdgcn_mfma_f32_16x16x32_bf16(bk0, aq[0], sacc[t], 0, 0, 0);
            sacc[t] = __builtin_amdgcn_mfma_f32_16x16x32_bf16(bk1, aq[1], sacc[t], 0, 0, 0);
        }

        const bool need_mask = (j0 == q0) || (q0 >= WIN && j0 == kstart);
        float sv[4][4];
        if (need_mask) {
#pragma unroll
            for (int t = 0; t < 4; ++t)
#pragma unroll
                for (int r = 0; r < 4; ++r) {
                    int j = j0 + t * 16 + quad * 4 + r;
                    bool ok = (j <= qi) && (j + WIN >= qi);
                    sv[t][r] = ok ? sacc[t][r] * SL2 : -1e30f;
                }
        } else {
#pragma unroll
            for (int t = 0; t < 4; ++t)
#pragma unroll
                for (int r = 0; r < 4; ++r) sv[t][r] = sacc[t][r] * SL2;
        }
        // online softmax (exp2 domain): in-lane reduce + 2 shuffles
        float cm = -1e30f;
#pragma unroll
        for (int t = 0; t < 4; ++t)
#pragma unroll
            for (int r = 0; r < 4; ++r) cm = fmaxf(cm, sv[t][r]);
        cm = fmaxf(cm, __shfl_xor(cm, 16));
        cm = fmaxf(cm, __shfl_xor(cm, 32));
        // T13 defer-max: skip rescale while the tile max stays within 8
        // (exp2 domain) of the running max; P then bounded by 2^8 = 256.
        if (!__all(cm - m <= 8.0f)) {
            float mn = fmaxf(m, cm);
            float alpha = exp2f(m - mn);
            m = mn;
            l *= alpha;
#pragma unroll
            for (int t = 0; t < 4; ++t)
#pragma unroll
                for (int r = 0; r < 4; ++r) acc_o[t][r] *= alpha;
        }
        float sp = 0.f;
#pragma unroll
        for (int t = 0; t < 4; ++t)
#pragma unroll
            for (int r = 0; r < 4; ++r) { sv[t][r] = exp2f(sv[t][r] - m); sp += sv[t][r]; }
        sp += __shfl_xor(sp, 16);
        sp += __shfl_xor(sp, 32);
        l += sp;
        // P^T -> LDS (XOR unit swizzle; wave-private, in-order)
#pragma unroll
        for (int t = 0; t < 4; ++t) {
            alignas(8) __hip_bfloat16 hp[4];
#pragma unroll
            for (int r = 0; r < 4; ++r) hp[r] = __float2bfloat16(sv[t][r]);
            int swb = ((((2 * t + (quad >> 1)) ^ (l16 & 7)) << 4) | ((quad & 1) << 3));
            *reinterpret_cast<ushort4*>(prow + swb) = *reinterpret_cast<ushort4*>(hp);
        }

        // O^T += VT @ P^T
#pragma unroll
        for (int ks = 0; ks < 2; ++ks) {
            short8 pf = *reinterpret_cast<const short8*>(
                prow + (((4 * ks + quad) ^ (l16 & 7)) << 4));
#pragma unroll
            for (int t = 0; t < 4; ++t) {
                const __hip_bfloat16* vrow = &ldsVT[buf][t * 16 + l16][0];
                short8 vf = *reinterpret_cast<const short8*>(
                    vrow + (((ks * 4 + quad) ^ sw) * 8));
                acc_o[t] = __builtin_amdgcn_mfma_f32_16x16x32_bf16(vf, pf, acc_o[t], 0, 0, 0);
            }
        }
        buf ^= 1;
    }

    {
        float inv = 1.f / l;
        __hip_bfloat16* op =
            O + (size_t)(b * S_LEN + qi) * (NH * HD) + h * HD;
#pragma unroll
        for (int t = 0; t < 4; ++t) {
            alignas(8) __hip_bfloat16 ho[4];
#pragma unroll
            for (int r = 0; r < 4; ++r) ho[r] = __float2bfloat16(acc_o[t][r] * inv);
            *reinterpret_cast<ushort4*>(op + t * 16 + quad * 4) =
                *reinterpret_cast<ushort4*>(ho);
        }
    }
}

// ---------------- launch ----------------
extern "C" void kernel_launch(void* const* d_in, const int* in_sizes, int n_in,
                              void* d_out, int out_size, void* d_ws, size_t ws_size,
                              hipStream_t stream) {
    const float* X  = (const float*)d_in[0];
    const float* Wq = (const float*)d_in[1];
    const float* Wk = (const float*)d_in[2];
    const float* Wv = (const float*)d_in[3];
    const float* Wo = (const float*)d_in[4];
    float* out = (float*)d_out;

    const int ROWS = 2 * S_LEN;               // 4096
    char* ws = (char*)d_ws;
    size_t off = 0;
    __hip_bfloat16* Xb     = (__hip_bfloat16*)(ws + off); off += (size_t)ROWS * DMODEL * 2;
    __hip_bfloat16* WqkvT  = (__hip_bfloat16*)(ws + off); off += (size_t)2048 * DMODEL * 2;
    __hip_bfloat16* WoT    = (__hip_bfloat16*)(ws + off); off += (size_t)DMODEL * DMODEL * 2;
    __hip_bfloat16* Qb     = (__hip_bfloat16*)(ws + off); off += (size_t)ROWS * (NH * HD) * 2;
    __hip_bfloat16* Kb     = (__hip_bfloat16*)(ws + off); off += (size_t)ROWS * (NKV * HD) * 2;
    __hip_bfloat16* VTg    = (__hip_bfloat16*)(ws + off); off += (size_t)ROWS * (NKV * HD) * 2;
    __hip_bfloat16* Ob     = (__hip_bfloat16*)(ws + off); off += (size_t)ROWS * (NH * HD) * 2;

    // 1. fused prep: X cast (z=4) + all weight transposes (z=0..3)
    prep_kernel<<<dim3(32, 32, 5), dim3(32, 8), 0, stream>>>(
        X, Wq, Wk, Wv, Wo, Xb, WqkvT, WoT);

    // 2. fused QKV projection + RoPE + V transpose (128x128 tile, 512 blocks)
    gemm_qkv_kernel<<<dim3(2048 / 128, ROWS / 128), 256, 0, stream>>>(
        Xb, WqkvT, Qb, Kb, VTg);

    // 3. MFMA flash attention (QBLK=64, staged DMA dbuf — measured best)
    attn_mfma_kernel<<<dim3(S_LEN / 64, NH, 2), 256, 0, stream>>>(Qb, Kb, VTg, Ob);

    // 4. output projection -> fp32 (r16 measured-best config)
    gemm_op_kernel<<<dim3(DMODEL / 64, ROWS / 128), 256, 0, stream>>>(
        Ob, WoT, out, DMODEL, DMODEL);
}

// Round 12
// 145.171 us; speedup vs baseline: 1.2914x; 1.0096x over previous
//
#include <hip/hip_runtime.h>
#include <hip/hip_bf16.h>

typedef __attribute__((ext_vector_type(8))) short short8;
typedef __attribute__((ext_vector_type(4))) float f32x4;

#define S_LEN 2048
#define NH 16
#define NKV 8
#define HD 64
#define WIN 512
#define DMODEL 1024
#define LOG2_10000 13.287712379549449f

// async 16B global -> LDS (wave-uniform LDS base + lane*16 semantics)
#define GLOAD16(g, l)                                                        \
    __builtin_amdgcn_global_load_lds(                                        \
        (const __attribute__((address_space(1))) unsigned int*)(g),          \
        (__attribute__((address_space(3))) unsigned int*)(l), 16, 0, 0)

// T1 XCD-aware chunked bijective swizzle (m204; requires nwg % 8 == 0):
// dispatched block `lin` (XCD = lin%8) computes work-tile (lin%8)*(nwg/8)+lin/8
// -> each XCD owns a contiguous chunk of work-tiles, so blocks sharing an
// A-panel / K-V slice land on the same XCD L2.
__device__ __forceinline__ int xcd_swz(int lin, int nwg) {
    return (lin & 7) * (nwg >> 3) + (lin >> 3);
}

// ------- prep: fused X-cast (z=4) + transpose+cast of 4 weights (z=0..3) ----
__global__ void prep_kernel(const float* __restrict__ X,
                            const float* __restrict__ W0,
                            const float* __restrict__ W1,
                            const float* __restrict__ W2,
                            const float* __restrict__ W3,
                            __hip_bfloat16* __restrict__ Xb,
                            __hip_bfloat16* __restrict__ WqkvT,
                            __hip_bfloat16* __restrict__ WoT) {
    if (blockIdx.z == 4) {                         // X cast: fp32 -> bf16
        int tid = (blockIdx.y * 32 + blockIdx.x) * 256 + threadIdx.y * 32 + threadIdx.x;
        const float4* Xi = reinterpret_cast<const float4*>(X);
#pragma unroll
        for (int r = 0; r < 4; ++r) {
            int i = tid + r * (1024 * 256);        // float4 index
            float4 v = Xi[i];
            alignas(8) __hip_bfloat16 h[4];
            h[0] = __float2bfloat16(v.x);
            h[1] = __float2bfloat16(v.y);
            h[2] = __float2bfloat16(v.z);
            h[3] = __float2bfloat16(v.w);
            *reinterpret_cast<ushort4*>(Xb + (size_t)i * 4) =
                *reinterpret_cast<ushort4*>(h);
        }
        return;
    }
    __shared__ float tile[32][33];
    const int K = DMODEL;
    const float* W;
    __hip_bfloat16* WT;
    int N;
    switch (blockIdx.z) {
        case 0: W = W0; WT = WqkvT;                          N = 1024; break;
        case 1: W = W1; WT = WqkvT + (size_t)1024 * K;       N = 512;  break;
        case 2: W = W2; WT = WqkvT + (size_t)1536 * K;       N = 512;  break;
        default: W = W3; WT = WoT;                           N = 1024; break;
    }
    if ((int)blockIdx.x * 32 >= N) return;
    int nx = blockIdx.x * 32 + threadIdx.x;
    int k0 = blockIdx.y * 32;
#pragma unroll
    for (int r = 0; r < 4; ++r) {
        int k = k0 + threadIdx.y + r * 8;
        tile[threadIdx.y + r * 8][threadIdx.x] = W[(size_t)k * N + nx];
    }
    __syncthreads();
#pragma unroll
    for (int r = 0; r < 4; ++r) {
        int nn = blockIdx.x * 32 + threadIdx.y + r * 8;
        int kk = k0 + threadIdx.x;
        WT[(size_t)nn * K + kk] = __float2bfloat16(tile[threadIdx.x][threadIdx.y + r * 8]);
    }
}

// ---------- QKV GEMM: 128x128 tile, 4 waves (2x2 of 64x64), BK=64 ----------
// ROUND 17: 64x64 wave-tile: 16 ds_read vs 32 MFMA per wave-iteration —
// MFMA-dominant. Both-sides XOR involution on the 128 B LDS rows (rule #21).
// Grid 512 = 2 blocks/CU: independent blocks overlap each other's drains.
// ROUND 22: + T1 XCD swizzle (measured best 146.07). FROZEN.
__global__ __launch_bounds__(256, 2) void gemm_qkv_kernel(
    const __hip_bfloat16* __restrict__ A,
    const __hip_bfloat16* __restrict__ BT,
    __hip_bfloat16* __restrict__ Qo,
    __hip_bfloat16* __restrict__ Ko,
    __hip_bfloat16* __restrict__ VTo) {
    const int K = DMODEL;
    __shared__ __hip_bfloat16 ldsA[2][128 * 64];   // 32 KB
    __shared__ __hip_bfloat16 ldsB[2][128 * 64];   // 32 KB
    const int tx = threadIdx.x;
    const int wave = tx >> 6;
    const int lane = tx & 63;
    const int l16 = lane & 15;
    const int quad = lane >> 4;
    const int swz = xcd_swz(blockIdx.x + 16 * blockIdx.y, 512);
    const int col0 = (swz & 15) * 128;
    const int row0 = (swz >> 4) * 128;
    const int wrow = (wave >> 1) * 64;
    const int wcol = (wave & 1) * 64;
    const int sw = l16 & 7;                        // reader swizzle key

    f32x4 acc[4][4] = {};

    // staging: row = tx>>3 (0..31), chunk = tx&7, XOR source swizzle
    const int arow = tx >> 3;
    const int cs8 = ((tx & 7) ^ (arow & 7)) * 8;   // swizzled source chunk
    const __hip_bfloat16* gA = A + (size_t)(row0 + arow) * K + cs8;
    const __hip_bfloat16* gB = BT + (size_t)(col0 + arow) * K + cs8;

    auto stage = [&](int k0, int bf) {
        char* lA = (char*)(&ldsA[bf][0]) + tx * 16;
        char* lB = (char*)(&ldsB[bf][0]) + tx * 16;
#pragma unroll
        for (int r = 0; r < 4; ++r) {              // rows r*32 .. r*32+31
            GLOAD16(gA + (size_t)(r * 32) * K + k0, lA + r * 4096);
            GLOAD16(gB + (size_t)(r * 32) * K + k0, lB + r * 4096);
        }
    };

    stage(0, 0);
    int buf = 0;
    for (int k0 = 0; k0 < K; k0 += 64) {
        __syncthreads();                            // drains DMA into [buf]
        if (k0 + 64 < K) stage(k0 + 64, buf ^ 1);   // lands by next barrier
        short8 af[4][2], bf4[4][2];
#pragma unroll
        for (int i = 0; i < 4; ++i) {
            const char* ar = (const char*)(&ldsA[buf][0]) + (wrow + i * 16 + l16) * 128;
            const char* br = (const char*)(&ldsB[buf][0]) + (wcol + i * 16 + l16) * 128;
#pragma unroll
            for (int ks = 0; ks < 2; ++ks) {
                af[i][ks] = *reinterpret_cast<const short8*>(
                    ar + (((ks * 4 + quad) ^ sw) << 4));
                bf4[i][ks] = *reinterpret_cast<const short8*>(
                    br + (((ks * 4 + quad) ^ sw) << 4));
            }
        }
#pragma unroll
        for (int ks = 0; ks < 2; ++ks)
#pragma unroll
            for (int mi = 0; mi < 4; ++mi)
#pragma unroll
                for (int ni = 0; ni < 4; ++ni)
                    acc[mi][ni] = __builtin_amdgcn_mfma_f32_16x16x32_bf16(
                        af[mi][ks], bf4[ni][ks], acc[mi][ni], 0, 0, 0);
        buf ^= 1;
    }

    const int rbase = row0 + wrow;
    const int cbaseg = col0 + wcol;                 // 64-aligned global col
    const bool isQ = (cbaseg < DMODEL);
    const bool isK = (cbaseg >= DMODEL) && (cbaseg < DMODEL + 512);
    if (isQ || isK) {
        float invf[2];
        invf[0] = exp2f(-(float)(l16)      * (LOG2_10000 / 32.0f));
        invf[1] = exp2f(-(float)(16 + l16) * (LOG2_10000 / 32.0f));
#pragma unroll
        for (int mi = 0; mi < 4; ++mi)
#pragma unroll
            for (int r = 0; r < 4; ++r) {
                int srow = (rbase + mi * 16 + quad * 4 + r) & (S_LEN - 1);
#pragma unroll
                for (int ni = 0; ni < 2; ++ni) {
                    float ang = (float)srow * invf[ni];
                    float c = __cosf(ang), s = __sinf(ang);
                    float x1 = acc[mi][ni][r], x2 = acc[mi][ni + 2][r];
                    acc[mi][ni][r]     = x1 * c - x2 * s;
                    acc[mi][ni + 2][r] = x2 * c + x1 * s;
                }
            }
        __hip_bfloat16* Co = isQ ? Qo : Ko;
        int cbase = isQ ? cbaseg : cbaseg - DMODEL;
        int rowstride = isQ ? (NH * HD) : (NKV * HD);
#pragma unroll
        for (int mi = 0; mi < 4; ++mi)
#pragma unroll
            for (int ni = 0; ni < 4; ++ni) {
                size_t col = cbase + ni * 16 + l16;
#pragma unroll
                for (int r = 0; r < 4; ++r)
                    Co[(size_t)(rbase + mi * 16 + quad * 4 + r) * rowstride + col] =
                        __float2bfloat16(acc[mi][ni][r]);
            }
    } else {                                       // V region -> transposed VT
        int bb = row0 >> 11;
#pragma unroll
        for (int mi = 0; mi < 4; ++mi) {
            int s = ((rbase + mi * 16 + quad * 4) & (S_LEN - 1));
#pragma unroll
            for (int ni = 0; ni < 4; ++ni) {
                int colv = cbaseg - 1536 + ni * 16 + l16;   // 0..511
                int vh = colv >> 6, d = colv & 63;
                alignas(8) __hip_bfloat16 hv[4];
#pragma unroll
                for (int r = 0; r < 4; ++r) hv[r] = __float2bfloat16(acc[mi][ni][r]);
                *reinterpret_cast<ushort4*>(
                    VTo + ((size_t)(bb * NKV + vh) * HD + d) * S_LEN + s) =
                    *reinterpret_cast<ushort4*>(hv);
            }
        }
    }
}

// ------- out-proj GEMM: 128(M)x64(N) tile, 4 waves of 32x64, BK=64 -------
// r16 measured-best config. Five variants tried (r18 128x128, r19 2-wave,
// r21 split-K atomics) all regressed — FROZEN structurally. + T1 swizzle.
__global__ __launch_bounds__(256, 4) void gemm_op_kernel(
    const __hip_bfloat16* __restrict__ A,
    const __hip_bfloat16* __restrict__ BT,
    float* __restrict__ Co, int N, int K) {
    __shared__ __hip_bfloat16 ldsA[2][128 * 64];   // 32 KB
    __shared__ __hip_bfloat16 ldsB[2][64 * 64];    // 16 KB
    const int tx = threadIdx.x;
    const int wave = tx >> 6;
    const int lane = tx & 63;
    const int l16 = lane & 15;
    const int quad = lane >> 4;
    const int swz = xcd_swz(blockIdx.x + 16 * blockIdx.y, 512);
    const int col0 = (swz & 15) * 64;
    const int row0 = (swz >> 4) * 128;
    const int wrow = wave * 32;
    const int sw = l16 & 7;                        // reader swizzle key

    f32x4 acc[2][4] = {};

    // staging: row = tx>>3 (0..31), chunk = tx&7, XOR source swizzle
    const int arow = tx >> 3;
    const int cs8 = ((tx & 7) ^ (arow & 7)) * 8;   // swizzled source chunk
    const __hip_bfloat16* gA = A + (size_t)(row0 + arow) * K + cs8;
    const __hip_bfloat16* gB = BT + (size_t)(col0 + arow) * K + cs8;

    auto stage = [&](int k0, int bf) {
        char* lA = (char*)(&ldsA[bf][0]) + tx * 16;
        char* lB = (char*)(&ldsB[bf][0]) + tx * 16;
#pragma unroll
        for (int r = 0; r < 4; ++r)                // A rows r*32 .. r*32+31
            GLOAD16(gA + (size_t)(r * 32) * K + k0, lA + r * 4096);
#pragma unroll
        for (int r = 0; r < 2; ++r)                // B rows r*32 .. r*32+31
            GLOAD16(gB + (size_t)(r * 32) * K + k0, lB + r * 4096);
    };

    stage(0, 0);
    int buf = 0;
    for (int k0 = 0; k0 < K; k0 += 64) {
        __syncthreads();                            // drains DMA into [buf]
        if (k0 + 64 < K) stage(k0 + 64, buf ^ 1);   // lands by next barrier
        short8 af[2][2], bf4[4][2];
#pragma unroll
        for (int i = 0; i < 2; ++i) {
            const char* ar = (const char*)(&ldsA[buf][0]) + (wrow + i * 16 + l16) * 128;
#pragma unroll
            for (int ks = 0; ks < 2; ++ks)
                af[i][ks] = *reinterpret_cast<const short8*>(
                    ar + (((ks * 4 + quad) ^ sw) << 4));
        }
#pragma unroll
        for (int i = 0; i < 4; ++i) {
            const char* br = (const char*)(&ldsB[buf][0]) + (i * 16 + l16) * 128;
#pragma unroll
            for (int ks = 0; ks < 2; ++ks)
                bf4[i][ks] = *reinterpret_cast<const short8*>(
                    br + (((ks * 4 + quad) ^ sw) << 4));
        }
#pragma unroll
        for (int ks = 0; ks < 2; ++ks)
#pragma unroll
            for (int mi = 0; mi < 2; ++mi)
#pragma unroll
                for (int ni = 0; ni < 4; ++ni)
                    acc[mi][ni] = __builtin_amdgcn_mfma_f32_16x16x32_bf16(
                        af[mi][ks], bf4[ni][ks], acc[mi][ni], 0, 0, 0);
        buf ^= 1;
    }

    const int rbase = row0 + wrow;
#pragma unroll
    for (int mi = 0; mi < 2; ++mi)
#pragma unroll
        for (int ni = 0; ni < 4; ++ni) {
            size_t col = col0 + ni * 16 + l16;
#pragma unroll
            for (int r = 0; r < 4; ++r)
                Co[(size_t)(rbase + mi * 16 + quad * 4 + r) * N + col] = acc[mi][ni][r];
        }
}

// ---------------- MFMA flash attention: head-split, DMA dbuf, swizzled ----
// QBLK=64 measured-best config (r17) + T1 XCD swizzle (r22, 146.07 best).
// r23's direct-L2 variant regressed 4.8x — LDS staging shares each K/V tile
// across 4 waves and keeps load latency off the MFMA path. Structure FROZEN.
// ROUND 25: + T5 s_setprio around the two MFMA clusters. Mechanism check
// (m190/m191): T5 needs wave role-diversity on the CU — here 4 INDEPENDENT
// blocks/CU sit at skewed j-phases (staging vs softmax-VALU vs MFMA), the
// m191 attn regime (+4-7%), unlike the lockstep-GEMM null (m190). Cost: 4
// SALU per j-tile. T13 defer-max retained.
__global__ __launch_bounds__(256, 4) void attn_mfma_kernel(
    const __hip_bfloat16* __restrict__ Q,
    const __hip_bfloat16* __restrict__ K,
    const __hip_bfloat16* __restrict__ VT,
    __hip_bfloat16* __restrict__ O) {
    __shared__ __hip_bfloat16 ldsK[2][64][64];       // 16 KB
    __shared__ __hip_bfloat16 ldsVT[2][64][64];      // 16 KB
    __shared__ __hip_bfloat16 ldsP[4][16][64];       // 8 KB, XOR unit swizzle
    const int tx = threadIdx.x;
    const int wave = tx >> 6;
    const int lane = tx & 63;
    const int l16 = lane & 15;
    const int quad = lane >> 4;
    const int swz = xcd_swz(blockIdx.x + 32 * (blockIdx.y + 16 * blockIdx.z), 1024);
    const int q0 = (swz & 31) * 64;
    const int h = (swz >> 5) & 15;
    const int b = swz >> 9;
    const int kvh = h >> 1;
    const int qi = q0 + wave * 16 + l16;

    short8 aq[2];
    {
        const __hip_bfloat16* qp =
            Q + (size_t)(b * S_LEN + qi) * (NH * HD) + h * HD + quad * 8;
        aq[0] = *reinterpret_cast<const short8*>(qp);
        aq[1] = *reinterpret_cast<const short8*>(qp + 32);
    }
    f32x4 acc_o[4] = {};
    float m = -1e30f, l = 0.f;
    const float SL2 = 0.125f * 1.4426950408889634f;   // scale * log2(e)

    // staging: row = tx>>3 (+32), chunk-in-row = tx&7, XOR source swizzle
    const int s_row = tx >> 3;
    const int s_c8 = (((tx & 7) ^ (s_row & 7))) * 8;
    const int sw = (l16 & 7);                          // reader swizzle key
    auto stage = [&](int j0, int bf) {
        char* lk = (char*)(&ldsK[bf][0][0]) + tx * 16;
        char* lv = (char*)(&ldsVT[bf][0][0]) + tx * 16;
#pragma unroll
        for (int r = 0; r < 2; ++r) {
            int row = s_row + r * 32;
            GLOAD16(K + (size_t)(b * S_LEN + j0 + row) * (NKV * HD) + kvh * HD + s_c8,
                    lk + r * 4096);
            GLOAD16(VT + ((size_t)(b * NKV + kvh) * HD + row) * S_LEN + j0 + s_c8,
                    lv + r * 4096);
        }
    };

    const int kstart = (q0 >= WIN) ? (q0 - WIN) : 0;
    stage(kstart, 0);
    int buf = 0;

    char* prow = (char*)(&ldsP[wave][l16][0]);

    for (int j0 = kstart; j0 <= q0; j0 += 64) {
        __syncthreads();                              // drains DMA into [buf]
        if (j0 + 64 <= q0) stage(j0 + 64, buf ^ 1);   // async, lands by next barrier

        // S^T = K @ Q^T   (T5: favor the MFMA-entering wave)
        f32x4 sacc[4] = {};
        __builtin_amdgcn_s_setprio(1);
#pragma unroll
        for (int t = 0; t < 4; ++t) {
            const __hip_bfloat16* krow = &ldsK[buf][t * 16 + l16][0];
            short8 bk0 = *reinterpret_cast<const short8*>(krow + ((quad ^ sw) * 8));
            short8 bk1 = *reinterpret_cast<const short8*>(krow + (((4 + quad) ^ sw) * 8));
            sacc[t] = __builtin_amdgcn_mfma_f32_16x16x32_bf16(bk0, aq[0], sacc[t], 0, 0, 0);
            sacc[t] = __builtin_amdgcn_mfma_f32_16x16x32_bf16(bk1, aq[1], sacc[t], 0, 0, 0);
        }
        __builtin_amdgcn_s_setprio(0);

        const bool need_mask = (j0 == q0) || (q0 >= WIN && j0 == kstart);
        float sv[4][4];
        if (need_mask) {
#pragma unroll
            for (int t = 0; t < 4; ++t)
#pragma unroll
                for (int r = 0; r < 4; ++r) {
                    int j = j0 + t * 16 + quad * 4 + r;
                    bool ok = (j <= qi) && (j + WIN >= qi);
                    sv[t][r] = ok ? sacc[t][r] * SL2 : -1e30f;
                }
        } else {
#pragma unroll
            for (int t = 0; t < 4; ++t)
#pragma unroll
                for (int r = 0; r < 4; ++r) sv[t][r] = sacc[t][r] * SL2;
        }
        // online softmax (exp2 domain): in-lane reduce + 2 shuffles
        float cm = -1e30f;
#pragma unroll
        for (int t = 0; t < 4; ++t)
#pragma unroll
            for (int r = 0; r < 4; ++r) cm = fmaxf(cm, sv[t][r]);
        cm = fmaxf(cm, __shfl_xor(cm, 16));
        cm = fmaxf(cm, __shfl_xor(cm, 32));
        // T13 defer-max: skip rescale while the tile max stays within 8
        // (exp2 domain) of the running max; P then bounded by 2^8 = 256.
        if (!__all(cm - m <= 8.0f)) {
            float mn = fmaxf(m, cm);
            float alpha = exp2f(m - mn);
            m = mn;
            l *= alpha;
#pragma unroll
            for (int t = 0; t < 4; ++t)
#pragma unroll
                for (int r = 0; r < 4; ++r) acc_o[t][r] *= alpha;
        }
        float sp = 0.f;
#pragma unroll
        for (int t = 0; t < 4; ++t)
#pragma unroll
            for (int r = 0; r < 4; ++r) { sv[t][r] = exp2f(sv[t][r] - m); sp += sv[t][r]; }
        sp += __shfl_xor(sp, 16);
        sp += __shfl_xor(sp, 32);
        l += sp;
        // P^T -> LDS (XOR unit swizzle; wave-private, in-order)
#pragma unroll
        for (int t = 0; t < 4; ++t) {
            alignas(8) __hip_bfloat16 hp[4];
#pragma unroll
            for (int r = 0; r < 4; ++r) hp[r] = __float2bfloat16(sv[t][r]);
            int swb = ((((2 * t + (quad >> 1)) ^ (l16 & 7)) << 4) | ((quad & 1) << 3));
            *reinterpret_cast<ushort4*>(prow + swb) = *reinterpret_cast<ushort4*>(hp);
        }

        // O^T += VT @ P^T   (T5: favor the MFMA-entering wave)
        __builtin_amdgcn_s_setprio(1);
#pragma unroll
        for (int ks = 0; ks < 2; ++ks) {
            short8 pf = *reinterpret_cast<const short8*>(
                prow + (((4 * ks + quad) ^ (l16 & 7)) << 4));
#pragma unroll
            for (int t = 0; t < 4; ++t) {
                const __hip_bfloat16* vrow = &ldsVT[buf][t * 16 + l16][0];
                short8 vf = *reinterpret_cast<const short8*>(
                    vrow + (((ks * 4 + quad) ^ sw) * 8));
                acc_o[t] = __builtin_amdgcn_mfma_f32_16x16x32_bf16(vf, pf, acc_o[t], 0, 0, 0);
            }
        }
        __builtin_amdgcn_s_setprio(0);
        buf ^= 1;
    }

    {
        float inv = 1.f / l;
        __hip_bfloat16* op =
            O + (size_t)(b * S_LEN + qi) * (NH * HD) + h * HD;
#pragma unroll
        for (int t = 0; t < 4; ++t) {
            alignas(8) __hip_bfloat16 ho[4];
#pragma unroll
            for (int r = 0; r < 4; ++r) ho[r] = __float2bfloat16(acc_o[t][r] * inv);
            *reinterpret_cast<ushort4*>(op + t * 16 + quad * 4) =
                *reinterpret_cast<ushort4*>(ho);
        }
    }
}

// ---------------- launch ----------------
extern "C" void kernel_launch(void* const* d_in, const int* in_sizes, int n_in,
                              void* d_out, int out_size, void* d_ws, size_t ws_size,
                              hipStream_t stream) {
    const float* X  = (const float*)d_in[0];
    const float* Wq = (const float*)d_in[1];
    const float* Wk = (const float*)d_in[2];
    const float* Wv = (const float*)d_in[3];
    const float* Wo = (const float*)d_in[4];
    float* out = (float*)d_out;

    const int ROWS = 2 * S_LEN;               // 4096
    char* ws = (char*)d_ws;
    size_t off = 0;
    __hip_bfloat16* Xb     = (__hip_bfloat16*)(ws + off); off += (size_t)ROWS * DMODEL * 2;
    __hip_bfloat16* WqkvT  = (__hip_bfloat16*)(ws + off); off += (size_t)2048 * DMODEL * 2;
    __hip_bfloat16* WoT    = (__hip_bfloat16*)(ws + off); off += (size_t)DMODEL * DMODEL * 2;
    __hip_bfloat16* Qb     = (__hip_bfloat16*)(ws + off); off += (size_t)ROWS * (NH * HD) * 2;
    __hip_bfloat16* Kb     = (__hip_bfloat16*)(ws + off); off += (size_t)ROWS * (NKV * HD) * 2;
    __hip_bfloat16* VTg    = (__hip_bfloat16*)(ws + off); off += (size_t)ROWS * (NKV * HD) * 2;
    __hip_bfloat16* Ob     = (__hip_bfloat16*)(ws + off); off += (size_t)ROWS * (NH * HD) * 2;

    // 1. fused prep: X cast (z=4) + all weight transposes (z=0..3)
    prep_kernel<<<dim3(32, 32, 5), dim3(32, 8), 0, stream>>>(
        X, Wq, Wk, Wv, Wo, Xb, WqkvT, WoT);

    // 2. fused QKV projection + RoPE + V transpose (128x128 tile, 512 blocks)
    gemm_qkv_kernel<<<dim3(2048 / 128, ROWS / 128), 256, 0, stream>>>(
        Xb, WqkvT, Qb, Kb, VTg);

    // 3. MFMA flash attention (QBLK=64, staged DMA dbuf + T5 setprio)
    attn_mfma_kernel<<<dim3(S_LEN / 64, NH, 2), 256, 0, stream>>>(Qb, Kb, VTg, Ob);

    // 4. output projection -> fp32 (r16 measured-best config)
    gemm_op_kernel<<<dim3(DMODEL / 64, ROWS / 128), 256, 0, stream>>>(
        Ob, WoT, out, DMODEL, DMODEL);
}